// Round 1
// 4329.065 us; speedup vs baseline: 1.9696x; 1.9696x over previous
//
#include <hip/hip_runtime.h>
#include <cstddef>

#define NN 50000
#define NE 640000
#define NB 4
#define H  128
#define NL 4
#define CH 16   // rows per tile for fp32 path (k_gemm_dual / k_node)
#define TE 64   // edges per block for MFMA edge kernel

typedef unsigned int u32;
typedef unsigned short u16;   // raw bf16 (intermediates only; I/O is fp32)
typedef __attribute__((ext_vector_type(8))) short bf16x8;
typedef __attribute__((ext_vector_type(4))) float f32x4;

__device__ __forceinline__ float bf2f(u16 s) {
    union { u32 u; float f; } v; v.u = ((u32)s) << 16; return v.f;
}
__device__ __forceinline__ u16 f2bf(float f) {
    union { float f; u32 u; } v; v.f = f;
    u32 u = v.u;
    u += 0x7FFF + ((u >> 16) & 1);   // RNE
    return (u16)(u >> 16);
}
__device__ __forceinline__ void unpack8(uint4 raw, float* d) {
    d[0] = bf2f(raw.x & 0xFFFF); d[1] = bf2f(raw.x >> 16);
    d[2] = bf2f(raw.y & 0xFFFF); d[3] = bf2f(raw.y >> 16);
    d[4] = bf2f(raw.z & 0xFFFF); d[5] = bf2f(raw.z >> 16);
    d[6] = bf2f(raw.w & 0xFFFF); d[7] = bf2f(raw.w >> 16);
}

// ---------------------------------------------------------------------------
// Tiled fp32 GEMM primitive (kept for k_gemm_dual / k_node): 128 threads;
// thread t owns output column t for CH rows staged in XL.
// ---------------------------------------------------------------------------
__device__ __forceinline__ void gemm_acc(float (*WL)[H + 4], float (*XL)[H + 8],
                                         const float* __restrict__ W,
                                         float acc[CH], int t) {
    for (int kh = 0; kh < H; kh += 64) {
        __syncthreads();
        {
            const int lk = t >> 1;            // 0..63 (W row kh+lk)
            const int cq = (t & 1) * 64;      // 0 or 64
            const float* wp = W + (size_t)(kh + lk) * H + cq;
#pragma unroll
            for (int s = 0; s < 64; s += 4)
                *(float4*)&WL[lk][cq + s] = *(const float4*)(wp + s);
        }
        __syncthreads();
#pragma unroll 2
        for (int k = 0; k < 64; k += 4) {
            const float w0 = WL[k + 0][t];
            const float w1 = WL[k + 1][t];
            const float w2 = WL[k + 2][t];
            const float w3 = WL[k + 3][t];
#pragma unroll
            for (int j = 0; j < CH; ++j) {
                const float4 ev = *(const float4*)&XL[j][kh + k];
                acc[j] = fmaf(ev.x, w0, acc[j]);
                acc[j] = fmaf(ev.y, w1, acc[j]);
                acc[j] = fmaf(ev.z, w2, acc[j]);
                acc[j] = fmaf(ev.w, w3, acc[j]);
            }
        }
    }
}

__device__ __forceinline__ void stage16_f32(float (*XL)[H + 8],
                                            const float* __restrict__ src, int t) {
    const int lr = t >> 3;           // 0..15
    const int kq = (t & 7) * 16;     // 0..112
#pragma unroll
    for (int s = 0; s < 16; s += 4)
        *(float4*)&XL[lr][kq + s] = *(const float4*)&src[(size_t)lr * H + kq + s];
}

// ---------------------------------------------------------------------------
__global__ __launch_bounds__(256) void k_zero(float* __restrict__ p, int n4) {
    const int i = blockIdx.x * 256 + threadIdx.x;
    if (i < n4) ((float4*)p)[i] = make_float4(0.f, 0.f, 0.f, 0.f);
}

// ---------------------------------------------------------------------------
// k_prep: per-layer edge weights -> bf16, transposed to [n][k] so MFMA
// B-fragments are contiguous 16B loads.  W1t[l][n][k] = pe_w1_c[l][k][n].
// ---------------------------------------------------------------------------
__global__ __launch_bounds__(256) void k_prep(
    const float* __restrict__ pe_w1, const float* __restrict__ pe_w2,
    u16* __restrict__ W1t, u16* __restrict__ W2t) {
    const int li = blockIdx.x;
    const float* src = blockIdx.y ? (pe_w2 + (size_t)li * H * H)
                                  : (pe_w1 + ((size_t)li * 512 + 256) * H);
    u16* dst = (blockIdx.y ? W2t : W1t) + (size_t)li * H * H;
    for (int idx = threadIdx.x; idx < H * H; idx += 256) {
        const int n = idx >> 7, k = idx & 127;
        dst[idx] = f2bf(src[(size_t)k * H + n]);
    }
}

// ---------------------------------------------------------------------------
// k_small (verified R13): u, x_cond, per-layer consts cbat/nbat.
// ---------------------------------------------------------------------------
__global__ __launch_bounds__(128) void k_small(
    const float* __restrict__ cond,
    const float* __restrict__ ecw1, const float* __restrict__ ecb1,
    const float* __restrict__ ecw2, const float* __restrict__ ecb2,
    const float* __restrict__ wv, const float* __restrict__ bv,
    const float* __restrict__ wo, const float* __restrict__ bo,
    const float* __restrict__ pe_w1, const float* __restrict__ pe_b1,
    const float* __restrict__ pn_w1, const float* __restrict__ pn_b1,
    float* __restrict__ cbat, float* __restrict__ nbat) {
    __shared__ float tmp[NB][H];
    __shared__ float uL[NB][H];
    __shared__ float xcL[NB][H];
    const int t = threadIdx.x;
    for (int b = 0; b < NB; ++b) {
        float a = ecb1[t];
        for (int k = 0; k < 10; ++k) a = fmaf(cond[b * 10 + k], ecw1[k * H + t], a);
        tmp[b][t] = fmaxf(a, 0.f);
    }
    __syncthreads();
    for (int b = 0; b < NB; ++b) {
        float a = ecb2[t];
        for (int k = 0; k < H; ++k) a = fmaf(tmp[b][k], ecw2[k * H + t], a);
        uL[b][t] = a;
    }
    __syncthreads();
    for (int b = 0; b < NB; ++b) {
        float a = bv[t];
        for (int k = 0; k < H; ++k) a = fmaf(uL[b][k], wv[k * H + t], a);
        tmp[b][t] = a;
    }
    __syncthreads();
    for (int b = 0; b < NB; ++b) {
        float a = bo[t];
        for (int k = 0; k < H; ++k) a = fmaf(tmp[b][k], wo[k * H + t], a);
        xcL[b][t] = a;
    }
    __syncthreads();
    for (int l = 0; l < NL; ++l) {
        const float* w1u = pe_w1 + ((size_t)l * 512 + 384) * H;
        for (int b = 0; b < NB; ++b) {
            float a = pe_b1[l * H + t];
            for (int k = 0; k < H; ++k) a = fmaf(uL[b][k], w1u[k * H + t], a);
            cbat[(l * NB + b) * H + t] = a;
        }
        const float* w1x = pn_w1 + ((size_t)l * 384 + 256) * H;
        for (int b = 0; b < NB; ++b) {
            float a = pn_b1[l * H + t];
            for (int k = 0; k < H; ++k) a = fmaf(xcL[b][k], w1x[k * H + t], a);
            nbat[(l * NB + b) * H + t] = a;
        }
    }
}

// ---------------------------------------------------------------------------
// Encoders / decoder: verified R13 naive versions.
// ---------------------------------------------------------------------------
template <int IN_DIM, bool OUT_BF16>
__global__ __launch_bounds__(128) void k_enc_n(
    const float* __restrict__ x,
    const float* __restrict__ w1, const float* __restrict__ b1,
    const float* __restrict__ w2, const float* __restrict__ b2,
    void* __restrict__ outv) {
    __shared__ float hid[H];
    const int t = threadIdx.x;
    const long long n = blockIdx.x;
    float a = b1[t];
#pragma unroll
    for (int k = 0; k < IN_DIM; ++k)
        a = fmaf(x[n * IN_DIM + k], w1[k * H + t], a);
    hid[t] = fmaxf(a, 0.f);
    __syncthreads();
    float v = b2[t];
    for (int k = 0; k < H; ++k) v = fmaf(hid[k], w2[k * H + t], v);
    if (OUT_BF16) ((u16*)outv)[n * H + t] = f2bf(v);
    else          ((float*)outv)[n * H + t] = v;
}

__global__ __launch_bounds__(128) void k_dec_n(
    const float* __restrict__ h,
    const float* __restrict__ w1, const float* __restrict__ b1,
    const float* __restrict__ w2, const float* __restrict__ b2,
    float* __restrict__ out) {
    __shared__ float hid[H];
    const int t = threadIdx.x;
    const long long n = blockIdx.x;
    float a = b1[t];
    for (int k = 0; k < H; ++k) a = fmaf(h[n * H + k], w1[k * H + t], a);
    hid[t] = fmaxf(a, 0.f);
    __syncthreads();
    if (t < 3) {
        float v = b2[t];
        for (int k = 0; k < H; ++k) v = fmaf(hid[k], w2[k * 3 + t], v);
        out[n * 3 + t] = v;
    }
}

// ---------------------------------------------------------------------------
// k_gemm_dual (tiled fp32): hA = h@Wa (y=0) / hB = h@Wb (y=1), bf16 out.
// ---------------------------------------------------------------------------
__global__ __launch_bounds__(128) void k_gemm_dual(
    const float* __restrict__ A,
    const float* __restrict__ Wa, const float* __restrict__ Wb,
    u16* __restrict__ Ca, u16* __restrict__ Cb) {
    __shared__ float WL[64][H + 4];
    __shared__ float XL[CH][H + 8];
    const int t = threadIdx.x;
    const long long n0 = (long long)blockIdx.x * CH;
    const float* W = blockIdx.y ? Wb : Wa;
    u16* C = blockIdx.y ? Cb : Ca;
    stage16_f32(XL, A + n0 * H, t);
    float acc[CH];
#pragma unroll
    for (int j = 0; j < CH; ++j) acc[j] = 0.f;
    gemm_acc(WL, XL, W, acc, t);
#pragma unroll
    for (int j = 0; j < CH; ++j) C[(size_t)(n0 + j) * H + t] = f2bf(acc[j]);
}

// ---------------------------------------------------------------------------
// k_edge_mfma: 64 edges/block, 256 threads (4 waves).  Wave w owns edges
// [w*16, w*16+16) of the tile, full 128-col output strip.
//   e' = relu(hA[row]+hB[col]+cbat[batch[row]] + e@W1c) @ W2 + b2
//   e = e' (bf16); agg[row] += e' (fp32 atomics)
// MFMA v_mfma_f32_16x16x32_bf16; A/B fragments loaded with the SAME slot->k
// mapping (k = ks*32 + (lane>>4)*8 + j) so any HW k-permutation cancels.
// C/D layout (verified): col = lane&15, row = (lane>>4)*4 + reg.
// ---------------------------------------------------------------------------
__global__ __launch_bounds__(256) void k_edge_mfma(
    const u16* __restrict__ hA, const u16* __restrict__ hB,
    const float* __restrict__ cbatl,
    const u16* __restrict__ W1t, const u16* __restrict__ W2t,
    const float* __restrict__ b2,
    const int* __restrict__ rowi, const int* __restrict__ coli,
    const int* __restrict__ batch,
    u16* __restrict__ e, float* __restrict__ agg) {
    __shared__ float SI[TE][H + 4];      // acc-init -> hidden -> output staging
    __shared__ int rL[TE], cL[TE], bL[TE];
    const int t = threadIdx.x;
    const long long e0 = (long long)blockIdx.x * TE;

    if (t < TE) {
        const int r = rowi[e0 + t];
        rL[t] = r; bL[t] = batch[r];
    } else if (t < 2 * TE) {
        cL[t - TE] = coli[e0 + t - TE];
    }
    __syncthreads();

    // stage acc-init = hA[row] + hB[col] + cbat[batch]  (16B loads, coalesced)
    for (int u = t; u < TE * 16; u += 256) {
        const int j = u >> 4, c8 = (u & 15) * 8;
        float va[8], vb[8];
        unpack8(*(const uint4*)&hA[(size_t)rL[j] * H + c8], va);
        unpack8(*(const uint4*)&hB[(size_t)cL[j] * H + c8], vb);
        const float* cb = &cbatl[bL[j] * H + c8];
#pragma unroll
        for (int q = 0; q < 8; ++q) SI[j][c8 + q] = va[q] + vb[q] + cb[q];
    }

    const int w = t >> 6, l = t & 63;
    const int m16 = l & 15, g = l >> 4;

    // A fragments (e tile) straight from global — contiguous 16B per lane
    bf16x8 afrag[4];
    {
        const u16* ep = e + (size_t)(e0 + w * 16 + m16) * H + g * 8;
#pragma unroll
        for (int ks = 0; ks < 4; ++ks) afrag[ks] = *(const bf16x8*)(ep + ks * 32);
    }
    __syncthreads();   // SI fill visible

    // ---- GEMM1: acc = init + e @ W1c ----
    f32x4 acc[8];
#pragma unroll
    for (int nt = 0; nt < 8; ++nt) {
#pragma unroll
        for (int j = 0; j < 4; ++j)
            acc[nt][j] = SI[w * 16 + g * 4 + j][nt * 16 + m16];
#pragma unroll
        for (int ks = 0; ks < 4; ++ks) {
            const bf16x8 bfr =
                *(const bf16x8*)&W1t[(size_t)(nt * 16 + m16) * H + ks * 32 + g * 8];
            acc[nt] = __builtin_amdgcn_mfma_f32_16x16x32_bf16(afrag[ks], bfr, acc[nt], 0, 0, 0);
        }
    }
    __syncthreads();

    // hidden = relu(acc) into SI (wave-own rows)
#pragma unroll
    for (int nt = 0; nt < 8; ++nt)
#pragma unroll
        for (int j = 0; j < 4; ++j)
            SI[w * 16 + g * 4 + j][nt * 16 + m16] = fmaxf(acc[nt][j], 0.f);
    __syncthreads();

    // ---- GEMM2: acc2 = b2 + hidden @ W2 ----
    f32x4 acc2[8];
#pragma unroll
    for (int nt = 0; nt < 8; ++nt) {
        const float bb = b2[nt * 16 + m16];
        acc2[nt][0] = bb; acc2[nt][1] = bb; acc2[nt][2] = bb; acc2[nt][3] = bb;
    }
#pragma unroll
    for (int ks = 0; ks < 4; ++ks) {
        bf16x8 a2;
        const float* hp = &SI[w * 16 + m16][ks * 32 + g * 8];
#pragma unroll
        for (int j = 0; j < 8; ++j) a2[j] = (short)f2bf(hp[j]);
#pragma unroll
        for (int nt = 0; nt < 8; ++nt) {
            const bf16x8 bfr =
                *(const bf16x8*)&W2t[(size_t)(nt * 16 + m16) * H + ks * 32 + g * 8];
            acc2[nt] = __builtin_amdgcn_mfma_f32_16x16x32_bf16(a2, bfr, acc2[nt], 0, 0, 0);
        }
    }
    __syncthreads();   // hidden reads done before overwrite

    // stage output back to SI for coalesced stores / atomics
#pragma unroll
    for (int nt = 0; nt < 8; ++nt)
#pragma unroll
        for (int j = 0; j < 4; ++j)
            SI[w * 16 + g * 4 + j][nt * 16 + m16] = acc2[nt][j];
    __syncthreads();

    // e write (packed bf16, 16B stores)
    for (int u = t; u < TE * 16; u += 256) {
        const int j = u >> 4, c8 = (u & 15) * 8;
        const float* sp = &SI[j][c8];
        uint4 pk;
        pk.x = (u32)f2bf(sp[0]) | ((u32)f2bf(sp[1]) << 16);
        pk.y = (u32)f2bf(sp[2]) | ((u32)f2bf(sp[3]) << 16);
        pk.z = (u32)f2bf(sp[4]) | ((u32)f2bf(sp[5]) << 16);
        pk.w = (u32)f2bf(sp[6]) | ((u32)f2bf(sp[7]) << 16);
        *(uint4*)&e[(size_t)(e0 + j) * H + c8] = pk;
    }
    // agg atomics, column-coalesced
    for (int idx = t; idx < TE * H; idx += 256) {
        const int j = idx >> 7, c = idx & 127;
        atomicAdd(&agg[(size_t)rL[j] * H + c], SI[j][c]);
    }
}

// ---------------------------------------------------------------------------
// k_node (tiled fp32): h += relu(h@Wn1a + agg@Wn1b + nbat[batch]) @ Wn2 + bn2
// ---------------------------------------------------------------------------
__global__ __launch_bounds__(128) void k_node(
    const float* __restrict__ Wn1a, const float* __restrict__ Wn1b,
    const float* __restrict__ Wn2, const float* __restrict__ bn2,
    const float* __restrict__ nbatl, const int* __restrict__ batch,
    const float* __restrict__ agg, float* __restrict__ h) {
    __shared__ float WL[64][H + 4];
    __shared__ float XL[CH][H + 8];
    __shared__ int bL[CH];
    const int t = threadIdx.x;
    const long long n0 = (long long)blockIdx.x * CH;
    if (t < CH) bL[t] = batch[n0 + t];
    stage16_f32(XL, h + n0 * H, t);
    __syncthreads();
    float acc[CH];
#pragma unroll
    for (int j = 0; j < CH; ++j) acc[j] = nbatl[bL[j] * H + t];
    gemm_acc(WL, XL, Wn1a, acc, t);
    __syncthreads();
    stage16_f32(XL, agg + n0 * H, t);
    gemm_acc(WL, XL, Wn1b, acc, t);
    __syncthreads();
#pragma unroll
    for (int j = 0; j < CH; ++j) XL[j][t] = fmaxf(acc[j], 0.f);
#pragma unroll
    for (int j = 0; j < CH; ++j) acc[j] = bn2[t];
    gemm_acc(WL, XL, Wn2, acc, t);
#pragma unroll
    for (int j = 0; j < CH; ++j) h[(size_t)(n0 + j) * H + t] += acc[j];
}

// ---------------------------------------------------------------------------
extern "C" void kernel_launch(void* const* d_in, const int* in_sizes, int n_in,
                              void* d_out, int out_size, void* d_ws, size_t ws_size,
                              hipStream_t stream) {
    const float* x          = (const float*)d_in[0];
    const int*   edge_index = (const int*)d_in[1];
    const float* edge_attr  = (const float*)d_in[2];
    const float* cond       = (const float*)d_in[3];
    const int*   batch      = (const int*)d_in[4];
    const float* enc_node_w1 = (const float*)d_in[5];
    const float* enc_node_b1 = (const float*)d_in[6];
    const float* enc_node_w2 = (const float*)d_in[7];
    const float* enc_node_b2 = (const float*)d_in[8];
    const float* enc_edge_w1 = (const float*)d_in[9];
    const float* enc_edge_b1 = (const float*)d_in[10];
    const float* enc_edge_w2 = (const float*)d_in[11];
    const float* enc_edge_b2 = (const float*)d_in[12];
    const float* enc_cond_w1 = (const float*)d_in[13];
    const float* enc_cond_b1 = (const float*)d_in[14];
    const float* enc_cond_w2 = (const float*)d_in[15];
    const float* enc_cond_b2 = (const float*)d_in[16];
    const float* attn_wv = (const float*)d_in[17];
    const float* attn_bv = (const float*)d_in[18];
    const float* attn_wo = (const float*)d_in[19];
    const float* attn_bo = (const float*)d_in[20];
    const float* pe_w1 = (const float*)d_in[21];
    const float* pe_b1 = (const float*)d_in[22];
    const float* pe_w2 = (const float*)d_in[23];
    const float* pe_b2 = (const float*)d_in[24];
    const float* pn_w1 = (const float*)d_in[25];
    const float* pn_b1 = (const float*)d_in[26];
    const float* pn_w2 = (const float*)d_in[27];
    const float* pn_b2 = (const float*)d_in[28];
    const float* dec_w1 = (const float*)d_in[29];
    const float* dec_b1 = (const float*)d_in[30];
    const float* dec_w2 = (const float*)d_in[31];
    const float* dec_b2 = (const float*)d_in[32];

    // workspace (~240.9 MB):
    u16*   e    = (u16*)d_ws;                                  // NE*H bf16
    float* h    = (float*)((char*)d_ws + (size_t)NE * H * 2);  // NN*H f32
    float* agg  = h + (size_t)NN * H;                          // NN*H f32
    u16*   hA   = (u16*)(agg + (size_t)NN * H);                // NN*H bf16
    u16*   hB   = hA + (size_t)NN * H;                         // NN*H bf16
    float* cbat = (float*)(hB + (size_t)NN * H);               // NL*NB*H f32
    float* nbat = cbat + NL * NB * H;                          // NL*NB*H f32
    u16*   W1t  = (u16*)(nbat + NL * NB * H);                  // NL*H*H bf16 (transposed)
    u16*   W2t  = W1t + (size_t)NL * H * H;                    // NL*H*H bf16 (transposed)

    const int* rowi = edge_index;
    const int* coli = edge_index + NE;
    float* out = (float*)d_out;

    k_prep<<<dim3(NL, 2), 256, 0, stream>>>(pe_w1, pe_w2, W1t, W2t);
    k_small<<<1, 128, 0, stream>>>(cond, enc_cond_w1, enc_cond_b1, enc_cond_w2, enc_cond_b2,
                                   attn_wv, attn_bv, attn_wo, attn_bo,
                                   pe_w1, pe_b1, pn_w1, pn_b1, cbat, nbat);
    k_enc_n<12, false><<<NN, 128, 0, stream>>>(
        x, enc_node_w1, enc_node_b1, enc_node_w2, enc_node_b2, (void*)h);
    k_enc_n<4, true><<<NE, 128, 0, stream>>>(
        edge_attr, enc_edge_w1, enc_edge_b1, enc_edge_w2, enc_edge_b2, (void*)e);

    for (int l = 0; l < NL; ++l) {
        k_zero<<<(NN * H / 4 + 255) / 256, 256, 0, stream>>>(agg, NN * H / 4);
        k_gemm_dual<<<dim3((NN + CH - 1) / CH, 2), 128, 0, stream>>>(
            h, pe_w1 + (size_t)l * 512 * H, pe_w1 + ((size_t)l * 512 + 128) * H, hA, hB);
        k_edge_mfma<<<NE / TE, 256, 0, stream>>>(
            hA, hB, cbat + l * NB * H,
            W1t + (size_t)l * H * H, W2t + (size_t)l * H * H,
            pe_b2 + l * H, rowi, coli, batch, e, agg);
        k_node<<<(NN + CH - 1) / CH, 128, 0, stream>>>(
            pn_w1 + (size_t)l * 384 * H, pn_w1 + ((size_t)l * 384 + 128) * H,
            pn_w2 + (size_t)l * H * H, pn_b2 + l * H,
            nbat + l * NB * H, batch, agg, h);
    }
    k_dec_n<<<NN, 128, 0, stream>>>(h, dec_w1, dec_b1, dec_w2, dec_b2, out);
}

// Round 2
// 3322.528 us; speedup vs baseline: 2.5663x; 1.3029x over previous
//
#include <hip/hip_runtime.h>
#include <cstddef>

#define NN 50000
#define NE 640000
#define NB 4
#define H  128
#define NL 4
#define CH 16   // rows per tile for fp32 path (k_gemm_dual / k_node)
#define TE 64   // edges per block for MFMA kernels

typedef unsigned int u32;
typedef unsigned short u16;   // raw bf16 (intermediates only; I/O is fp32)
typedef __attribute__((ext_vector_type(8))) short bf16x8;
typedef __attribute__((ext_vector_type(4))) float f32x4;

__device__ __forceinline__ float bf2f(u16 s) {
    union { u32 u; float f; } v; v.u = ((u32)s) << 16; return v.f;
}
__device__ __forceinline__ u16 f2bf(float f) {
    union { float f; u32 u; } v; v.f = f;
    u32 u = v.u;
    u += 0x7FFF + ((u >> 16) & 1);   // RNE
    return (u16)(u >> 16);
}
__device__ __forceinline__ void unpack8(uint4 raw, float* d) {
    d[0] = bf2f(raw.x & 0xFFFF); d[1] = bf2f(raw.x >> 16);
    d[2] = bf2f(raw.y & 0xFFFF); d[3] = bf2f(raw.y >> 16);
    d[4] = bf2f(raw.z & 0xFFFF); d[5] = bf2f(raw.z >> 16);
    d[6] = bf2f(raw.w & 0xFFFF); d[7] = bf2f(raw.w >> 16);
}

// ---------------------------------------------------------------------------
// Tiled fp32 GEMM primitive (kept for k_gemm_dual / k_node): 128 threads;
// thread t owns output column t for CH rows staged in XL.
// ---------------------------------------------------------------------------
__device__ __forceinline__ void gemm_acc(float (*WL)[H + 4], float (*XL)[H + 8],
                                         const float* __restrict__ W,
                                         float acc[CH], int t) {
    for (int kh = 0; kh < H; kh += 64) {
        __syncthreads();
        {
            const int lk = t >> 1;            // 0..63 (W row kh+lk)
            const int cq = (t & 1) * 64;      // 0 or 64
            const float* wp = W + (size_t)(kh + lk) * H + cq;
#pragma unroll
            for (int s = 0; s < 64; s += 4)
                *(float4*)&WL[lk][cq + s] = *(const float4*)(wp + s);
        }
        __syncthreads();
#pragma unroll 2
        for (int k = 0; k < 64; k += 4) {
            const float w0 = WL[k + 0][t];
            const float w1 = WL[k + 1][t];
            const float w2 = WL[k + 2][t];
            const float w3 = WL[k + 3][t];
#pragma unroll
            for (int j = 0; j < CH; ++j) {
                const float4 ev = *(const float4*)&XL[j][kh + k];
                acc[j] = fmaf(ev.x, w0, acc[j]);
                acc[j] = fmaf(ev.y, w1, acc[j]);
                acc[j] = fmaf(ev.z, w2, acc[j]);
                acc[j] = fmaf(ev.w, w3, acc[j]);
            }
        }
    }
}

__device__ __forceinline__ void stage16_f32(float (*XL)[H + 8],
                                            const float* __restrict__ src, int t) {
    const int lr = t >> 3;           // 0..15
    const int kq = (t & 7) * 16;     // 0..112
#pragma unroll
    for (int s = 0; s < 16; s += 4)
        *(float4*)&XL[lr][kq + s] = *(const float4*)&src[(size_t)lr * H + kq + s];
}

// ---------------------------------------------------------------------------
__global__ __launch_bounds__(256) void k_zero(float* __restrict__ p, int n4) {
    const int i = blockIdx.x * 256 + threadIdx.x;
    if (i < n4) ((float4*)p)[i] = make_float4(0.f, 0.f, 0.f, 0.f);
}

// ---------------------------------------------------------------------------
// k_prep: weights -> bf16, transposed to [n][k] for contiguous MFMA B-frags.
//   y=0: W1t[l] = pe_w1_c[l]^T   y=1: W2t[l] = pe_w2[l]^T
//   y=2 (li==0 only): W2et = enc_edge_w2^T
// ---------------------------------------------------------------------------
__global__ __launch_bounds__(256) void k_prep(
    const float* __restrict__ pe_w1, const float* __restrict__ pe_w2,
    const float* __restrict__ ew2,
    u16* __restrict__ W1t, u16* __restrict__ W2t, u16* __restrict__ W2et) {
    const int li = blockIdx.x;
    const float* src;
    u16* dst;
    if (blockIdx.y == 0) {
        src = pe_w1 + ((size_t)li * 512 + 256) * H; dst = W1t + (size_t)li * H * H;
    } else if (blockIdx.y == 1) {
        src = pe_w2 + (size_t)li * H * H;           dst = W2t + (size_t)li * H * H;
    } else {
        if (li) return;
        src = ew2;                                  dst = W2et;
    }
    for (int idx = threadIdx.x; idx < H * H; idx += 256) {
        const int n = idx >> 7, k = idx & 127;
        dst[idx] = f2bf(src[(size_t)k * H + n]);
    }
}

// ---------------------------------------------------------------------------
// k_small (verified R13): u, x_cond, per-layer consts cbat/nbat.
// ---------------------------------------------------------------------------
__global__ __launch_bounds__(128) void k_small(
    const float* __restrict__ cond,
    const float* __restrict__ ecw1, const float* __restrict__ ecb1,
    const float* __restrict__ ecw2, const float* __restrict__ ecb2,
    const float* __restrict__ wv, const float* __restrict__ bv,
    const float* __restrict__ wo, const float* __restrict__ bo,
    const float* __restrict__ pe_w1, const float* __restrict__ pe_b1,
    const float* __restrict__ pn_w1, const float* __restrict__ pn_b1,
    float* __restrict__ cbat, float* __restrict__ nbat) {
    __shared__ float tmp[NB][H];
    __shared__ float uL[NB][H];
    __shared__ float xcL[NB][H];
    const int t = threadIdx.x;
    for (int b = 0; b < NB; ++b) {
        float a = ecb1[t];
        for (int k = 0; k < 10; ++k) a = fmaf(cond[b * 10 + k], ecw1[k * H + t], a);
        tmp[b][t] = fmaxf(a, 0.f);
    }
    __syncthreads();
    for (int b = 0; b < NB; ++b) {
        float a = ecb2[t];
        for (int k = 0; k < H; ++k) a = fmaf(tmp[b][k], ecw2[k * H + t], a);
        uL[b][t] = a;
    }
    __syncthreads();
    for (int b = 0; b < NB; ++b) {
        float a = bv[t];
        for (int k = 0; k < H; ++k) a = fmaf(uL[b][k], wv[k * H + t], a);
        tmp[b][t] = a;
    }
    __syncthreads();
    for (int b = 0; b < NB; ++b) {
        float a = bo[t];
        for (int k = 0; k < H; ++k) a = fmaf(tmp[b][k], wo[k * H + t], a);
        xcL[b][t] = a;
    }
    __syncthreads();
    for (int l = 0; l < NL; ++l) {
        const float* w1u = pe_w1 + ((size_t)l * 512 + 384) * H;
        for (int b = 0; b < NB; ++b) {
            float a = pe_b1[l * H + t];
            for (int k = 0; k < H; ++k) a = fmaf(uL[b][k], w1u[k * H + t], a);
            cbat[(l * NB + b) * H + t] = a;
        }
        const float* w1x = pn_w1 + ((size_t)l * 384 + 256) * H;
        for (int b = 0; b < NB; ++b) {
            float a = pn_b1[l * H + t];
            for (int k = 0; k < H; ++k) a = fmaf(xcL[b][k], w1x[k * H + t], a);
            nbat[(l * NB + b) * H + t] = a;
        }
    }
}

// ---------------------------------------------------------------------------
// Node encoder / decoder: verified R13 naive versions.
// ---------------------------------------------------------------------------
template <int IN_DIM, bool OUT_BF16>
__global__ __launch_bounds__(128) void k_enc_n(
    const float* __restrict__ x,
    const float* __restrict__ w1, const float* __restrict__ b1,
    const float* __restrict__ w2, const float* __restrict__ b2,
    void* __restrict__ outv) {
    __shared__ float hid[H];
    const int t = threadIdx.x;
    const long long n = blockIdx.x;
    float a = b1[t];
#pragma unroll
    for (int k = 0; k < IN_DIM; ++k)
        a = fmaf(x[n * IN_DIM + k], w1[k * H + t], a);
    hid[t] = fmaxf(a, 0.f);
    __syncthreads();
    float v = b2[t];
    for (int k = 0; k < H; ++k) v = fmaf(hid[k], w2[k * H + t], v);
    if (OUT_BF16) ((u16*)outv)[n * H + t] = f2bf(v);
    else          ((float*)outv)[n * H + t] = v;
}

__global__ __launch_bounds__(128) void k_dec_n(
    const float* __restrict__ h,
    const float* __restrict__ w1, const float* __restrict__ b1,
    const float* __restrict__ w2, const float* __restrict__ b2,
    float* __restrict__ out) {
    __shared__ float hid[H];
    const int t = threadIdx.x;
    const long long n = blockIdx.x;
    float a = b1[t];
    for (int k = 0; k < H; ++k) a = fmaf(h[n * H + k], w1[k * H + t], a);
    hid[t] = fmaxf(a, 0.f);
    __syncthreads();
    if (t < 3) {
        float v = b2[t];
        for (int k = 0; k < H; ++k) v = fmaf(hid[k], w2[k * 3 + t], v);
        out[n * 3 + t] = v;
    }
}

// ---------------------------------------------------------------------------
// k_enc_e_mfma: edge encoder, 64 edges/block, 256 threads (4 waves).
//   hidden = relu(ea @ w1 + b1)  — K=4, computed per-lane DIRECTLY into the
//   MFMA A-fragment layout (col = ks*32 + g*8 + j).
//   e = hidden @ w2 + b2         — MFMA with pre-transposed bf16 W2et.
// Same symmetric slot->k mapping as k_edge_mfma (harness-verified).
// ---------------------------------------------------------------------------
__global__ __launch_bounds__(256) void k_enc_e_mfma(
    const float* __restrict__ ea,                         // [E,4]
    const float* __restrict__ w1, const float* __restrict__ b1,
    const u16* __restrict__ W2et, const float* __restrict__ b2,
    u16* __restrict__ e) {
    __shared__ float SI[TE][H + 4];
    const int t = threadIdx.x;
    const long long e0 = (long long)blockIdx.x * TE;
    const int w = t >> 6, l = t & 63;
    const int m16 = l & 15, g = l >> 4;
    const int row = w * 16 + m16;

    const float4 av = *(const float4*)&ea[(size_t)(e0 + row) * 4];

    // hidden fragment in registers (A-operand layout)
    bf16x8 afrag[4];
#pragma unroll
    for (int ks = 0; ks < 4; ++ks) {
        const int c0 = ks * 32 + g * 8;
        float hv[8];
        {
            const float4 ba = *(const float4*)&b1[c0];
            const float4 bb = *(const float4*)&b1[c0 + 4];
            hv[0] = ba.x; hv[1] = ba.y; hv[2] = ba.z; hv[3] = ba.w;
            hv[4] = bb.x; hv[5] = bb.y; hv[6] = bb.z; hv[7] = bb.w;
        }
#pragma unroll
        for (int k = 0; k < 4; ++k) {
            const float s = (k == 0) ? av.x : (k == 1) ? av.y : (k == 2) ? av.z : av.w;
            const float4 wa = *(const float4*)&w1[k * H + c0];
            const float4 wb = *(const float4*)&w1[k * H + c0 + 4];
            hv[0] = fmaf(s, wa.x, hv[0]); hv[1] = fmaf(s, wa.y, hv[1]);
            hv[2] = fmaf(s, wa.z, hv[2]); hv[3] = fmaf(s, wa.w, hv[3]);
            hv[4] = fmaf(s, wb.x, hv[4]); hv[5] = fmaf(s, wb.y, hv[5]);
            hv[6] = fmaf(s, wb.z, hv[6]); hv[7] = fmaf(s, wb.w, hv[7]);
        }
#pragma unroll
        for (int j = 0; j < 8; ++j) afrag[ks][j] = (short)f2bf(fmaxf(hv[j], 0.f));
    }

    // GEMM: acc = b2 + hidden @ w2
    f32x4 acc[8];
#pragma unroll
    for (int nt = 0; nt < 8; ++nt) {
        const float bb = b2[nt * 16 + m16];
        acc[nt][0] = bb; acc[nt][1] = bb; acc[nt][2] = bb; acc[nt][3] = bb;
    }
#pragma unroll
    for (int ks = 0; ks < 4; ++ks) {
#pragma unroll
        for (int nt = 0; nt < 8; ++nt) {
            const bf16x8 bfr =
                *(const bf16x8*)&W2et[(size_t)(nt * 16 + m16) * H + ks * 32 + g * 8];
            acc[nt] = __builtin_amdgcn_mfma_f32_16x16x32_bf16(afrag[ks], bfr, acc[nt], 0, 0, 0);
        }
    }

    // stage to SI, then packed coalesced bf16 stores
#pragma unroll
    for (int nt = 0; nt < 8; ++nt)
#pragma unroll
        for (int j = 0; j < 4; ++j)
            SI[w * 16 + g * 4 + j][nt * 16 + m16] = acc[nt][j];
    __syncthreads();
    for (int u = t; u < TE * 16; u += 256) {
        const int j = u >> 4, c8 = (u & 15) * 8;
        const float* sp = &SI[j][c8];
        uint4 pk;
        pk.x = (u32)f2bf(sp[0]) | ((u32)f2bf(sp[1]) << 16);
        pk.y = (u32)f2bf(sp[2]) | ((u32)f2bf(sp[3]) << 16);
        pk.z = (u32)f2bf(sp[4]) | ((u32)f2bf(sp[5]) << 16);
        pk.w = (u32)f2bf(sp[6]) | ((u32)f2bf(sp[7]) << 16);
        *(uint4*)&e[(size_t)(e0 + j) * H + c8] = pk;
    }
}

// ---------------------------------------------------------------------------
// k_gemm_dual (tiled fp32): hA = h@Wa (y=0) / hB = h@Wb (y=1), bf16 out.
// ---------------------------------------------------------------------------
__global__ __launch_bounds__(128) void k_gemm_dual(
    const float* __restrict__ A,
    const float* __restrict__ Wa, const float* __restrict__ Wb,
    u16* __restrict__ Ca, u16* __restrict__ Cb) {
    __shared__ float WL[64][H + 4];
    __shared__ float XL[CH][H + 8];
    const int t = threadIdx.x;
    const long long n0 = (long long)blockIdx.x * CH;
    const float* W = blockIdx.y ? Wb : Wa;
    u16* C = blockIdx.y ? Cb : Ca;
    stage16_f32(XL, A + n0 * H, t);
    float acc[CH];
#pragma unroll
    for (int j = 0; j < CH; ++j) acc[j] = 0.f;
    gemm_acc(WL, XL, W, acc, t);
#pragma unroll
    for (int j = 0; j < CH; ++j) C[(size_t)(n0 + j) * H + t] = f2bf(acc[j]);
}

// ---------------------------------------------------------------------------
// k_edge_mfma: 64 edges/block, 256 threads (4 waves).  Wave w owns edges
// [w*16, w*16+16) of the tile, full 128-col output strip.
//   e' = relu(hA[row]+hB[col]+cbat[batch[row]] + e@W1c) @ W2 + b2
//   e = e' (bf16); agg[row] += e' (fp32 atomics)
// ---------------------------------------------------------------------------
__global__ __launch_bounds__(256) void k_edge_mfma(
    const u16* __restrict__ hA, const u16* __restrict__ hB,
    const float* __restrict__ cbatl,
    const u16* __restrict__ W1t, const u16* __restrict__ W2t,
    const float* __restrict__ b2,
    const int* __restrict__ rowi, const int* __restrict__ coli,
    const int* __restrict__ batch,
    u16* __restrict__ e, float* __restrict__ agg) {
    __shared__ float SI[TE][H + 4];      // acc-init -> hidden -> output staging
    __shared__ int rL[TE], cL[TE], bL[TE];
    const int t = threadIdx.x;
    const long long e0 = (long long)blockIdx.x * TE;

    if (t < TE) {
        const int r = rowi[e0 + t];
        rL[t] = r; bL[t] = batch[r];
    } else if (t < 2 * TE) {
        cL[t - TE] = coli[e0 + t - TE];
    }
    __syncthreads();

    // stage acc-init = hA[row] + hB[col] + cbat[batch]  (16B loads, coalesced)
    for (int u = t; u < TE * 16; u += 256) {
        const int j = u >> 4, c8 = (u & 15) * 8;
        float va[8], vb[8];
        unpack8(*(const uint4*)&hA[(size_t)rL[j] * H + c8], va);
        unpack8(*(const uint4*)&hB[(size_t)cL[j] * H + c8], vb);
        const float* cb = &cbatl[bL[j] * H + c8];
#pragma unroll
        for (int q = 0; q < 8; ++q) SI[j][c8 + q] = va[q] + vb[q] + cb[q];
    }

    const int w = t >> 6, l = t & 63;
    const int m16 = l & 15, g = l >> 4;

    // A fragments (e tile) straight from global — contiguous 16B per lane
    bf16x8 afrag[4];
    {
        const u16* ep = e + (size_t)(e0 + w * 16 + m16) * H + g * 8;
#pragma unroll
        for (int ks = 0; ks < 4; ++ks) afrag[ks] = *(const bf16x8*)(ep + ks * 32);
    }
    __syncthreads();   // SI fill visible

    // ---- GEMM1: acc = init + e @ W1c ----
    f32x4 acc[8];
#pragma unroll
    for (int nt = 0; nt < 8; ++nt) {
#pragma unroll
        for (int j = 0; j < 4; ++j)
            acc[nt][j] = SI[w * 16 + g * 4 + j][nt * 16 + m16];
#pragma unroll
        for (int ks = 0; ks < 4; ++ks) {
            const bf16x8 bfr =
                *(const bf16x8*)&W1t[(size_t)(nt * 16 + m16) * H + ks * 32 + g * 8];
            acc[nt] = __builtin_amdgcn_mfma_f32_16x16x32_bf16(afrag[ks], bfr, acc[nt], 0, 0, 0);
        }
    }
    __syncthreads();

    // hidden = relu(acc) into SI (wave-own rows)
#pragma unroll
    for (int nt = 0; nt < 8; ++nt)
#pragma unroll
        for (int j = 0; j < 4; ++j)
            SI[w * 16 + g * 4 + j][nt * 16 + m16] = fmaxf(acc[nt][j], 0.f);
    __syncthreads();

    // ---- GEMM2: acc2 = b2 + hidden @ W2 ----
    f32x4 acc2[8];
#pragma unroll
    for (int nt = 0; nt < 8; ++nt) {
        const float bb = b2[nt * 16 + m16];
        acc2[nt][0] = bb; acc2[nt][1] = bb; acc2[nt][2] = bb; acc2[nt][3] = bb;
    }
#pragma unroll
    for (int ks = 0; ks < 4; ++ks) {
        bf16x8 a2;
        const float* hp = &SI[w * 16 + m16][ks * 32 + g * 8];
#pragma unroll
        for (int j = 0; j < 8; ++j) a2[j] = (short)f2bf(hp[j]);
#pragma unroll
        for (int nt = 0; nt < 8; ++nt) {
            const bf16x8 bfr =
                *(const bf16x8*)&W2t[(size_t)(nt * 16 + m16) * H + ks * 32 + g * 8];
            acc2[nt] = __builtin_amdgcn_mfma_f32_16x16x32_bf16(a2, bfr, acc2[nt], 0, 0, 0);
        }
    }
    __syncthreads();   // hidden reads done before overwrite

    // stage output back to SI for coalesced stores / atomics
#pragma unroll
    for (int nt = 0; nt < 8; ++nt)
#pragma unroll
        for (int j = 0; j < 4; ++j)
            SI[w * 16 + g * 4 + j][nt * 16 + m16] = acc2[nt][j];
    __syncthreads();

    // e write (packed bf16, 16B stores)
    for (int u = t; u < TE * 16; u += 256) {
        const int j = u >> 4, c8 = (u & 15) * 8;
        const float* sp = &SI[j][c8];
        uint4 pk;
        pk.x = (u32)f2bf(sp[0]) | ((u32)f2bf(sp[1]) << 16);
        pk.y = (u32)f2bf(sp[2]) | ((u32)f2bf(sp[3]) << 16);
        pk.z = (u32)f2bf(sp[4]) | ((u32)f2bf(sp[5]) << 16);
        pk.w = (u32)f2bf(sp[6]) | ((u32)f2bf(sp[7]) << 16);
        *(uint4*)&e[(size_t)(e0 + j) * H + c8] = pk;
    }
    // agg atomics, column-coalesced
    for (int idx = t; idx < TE * H; idx += 256) {
        const int j = idx >> 7, c = idx & 127;
        atomicAdd(&agg[(size_t)rL[j] * H + c], SI[j][c]);
    }
}

// ---------------------------------------------------------------------------
// k_node (tiled fp32): h += relu(h@Wn1a + agg@Wn1b + nbat[batch]) @ Wn2 + bn2
// ---------------------------------------------------------------------------
__global__ __launch_bounds__(128) void k_node(
    const float* __restrict__ Wn1a, const float* __restrict__ Wn1b,
    const float* __restrict__ Wn2, const float* __restrict__ bn2,
    const float* __restrict__ nbatl, const int* __restrict__ batch,
    const float* __restrict__ agg, float* __restrict__ h) {
    __shared__ float WL[64][H + 4];
    __shared__ float XL[CH][H + 8];
    __shared__ int bL[CH];
    const int t = threadIdx.x;
    const long long n0 = (long long)blockIdx.x * CH;
    if (t < CH) bL[t] = batch[n0 + t];
    stage16_f32(XL, h + n0 * H, t);
    __syncthreads();
    float acc[CH];
#pragma unroll
    for (int j = 0; j < CH; ++j) acc[j] = nbatl[bL[j] * H + t];
    gemm_acc(WL, XL, Wn1a, acc, t);
    __syncthreads();
    stage16_f32(XL, agg + n0 * H, t);
    gemm_acc(WL, XL, Wn1b, acc, t);
    __syncthreads();
#pragma unroll
    for (int j = 0; j < CH; ++j) XL[j][t] = fmaxf(acc[j], 0.f);
#pragma unroll
    for (int j = 0; j < CH; ++j) acc[j] = bn2[t];
    gemm_acc(WL, XL, Wn2, acc, t);
#pragma unroll
    for (int j = 0; j < CH; ++j) h[(size_t)(n0 + j) * H + t] += acc[j];
}

// ---------------------------------------------------------------------------
extern "C" void kernel_launch(void* const* d_in, const int* in_sizes, int n_in,
                              void* d_out, int out_size, void* d_ws, size_t ws_size,
                              hipStream_t stream) {
    const float* x          = (const float*)d_in[0];
    const int*   edge_index = (const int*)d_in[1];
    const float* edge_attr  = (const float*)d_in[2];
    const float* cond       = (const float*)d_in[3];
    const int*   batch      = (const int*)d_in[4];
    const float* enc_node_w1 = (const float*)d_in[5];
    const float* enc_node_b1 = (const float*)d_in[6];
    const float* enc_node_w2 = (const float*)d_in[7];
    const float* enc_node_b2 = (const float*)d_in[8];
    const float* enc_edge_w1 = (const float*)d_in[9];
    const float* enc_edge_b1 = (const float*)d_in[10];
    const float* enc_edge_w2 = (const float*)d_in[11];
    const float* enc_edge_b2 = (const float*)d_in[12];
    const float* enc_cond_w1 = (const float*)d_in[13];
    const float* enc_cond_b1 = (const float*)d_in[14];
    const float* enc_cond_w2 = (const float*)d_in[15];
    const float* enc_cond_b2 = (const float*)d_in[16];
    const float* attn_wv = (const float*)d_in[17];
    const float* attn_bv = (const float*)d_in[18];
    const float* attn_wo = (const float*)d_in[19];
    const float* attn_bo = (const float*)d_in[20];
    const float* pe_w1 = (const float*)d_in[21];
    const float* pe_b1 = (const float*)d_in[22];
    const float* pe_w2 = (const float*)d_in[23];
    const float* pe_b2 = (const float*)d_in[24];
    const float* pn_w1 = (const float*)d_in[25];
    const float* pn_b1 = (const float*)d_in[26];
    const float* pn_w2 = (const float*)d_in[27];
    const float* pn_b2 = (const float*)d_in[28];
    const float* dec_w1 = (const float*)d_in[29];
    const float* dec_b1 = (const float*)d_in[30];
    const float* dec_w2 = (const float*)d_in[31];
    const float* dec_b2 = (const float*)d_in[32];

    // workspace (~241 MB):
    u16*   e    = (u16*)d_ws;                                  // NE*H bf16
    float* h    = (float*)((char*)d_ws + (size_t)NE * H * 2);  // NN*H f32
    float* agg  = h + (size_t)NN * H;                          // NN*H f32
    u16*   hA   = (u16*)(agg + (size_t)NN * H);                // NN*H bf16
    u16*   hB   = hA + (size_t)NN * H;                         // NN*H bf16
    float* cbat = (float*)(hB + (size_t)NN * H);               // NL*NB*H f32
    float* nbat = cbat + NL * NB * H;                          // NL*NB*H f32
    u16*   W1t  = (u16*)(nbat + NL * NB * H);                  // NL*H*H bf16 (transposed)
    u16*   W2t  = W1t + (size_t)NL * H * H;                    // NL*H*H bf16 (transposed)
    u16*   W2et = W2t + (size_t)NL * H * H;                    // H*H bf16 (transposed)

    const int* rowi = edge_index;
    const int* coli = edge_index + NE;
    float* out = (float*)d_out;

    k_prep<<<dim3(NL, 3), 256, 0, stream>>>(pe_w1, pe_w2, enc_edge_w2, W1t, W2t, W2et);
    k_small<<<1, 128, 0, stream>>>(cond, enc_cond_w1, enc_cond_b1, enc_cond_w2, enc_cond_b2,
                                   attn_wv, attn_bv, attn_wo, attn_bo,
                                   pe_w1, pe_b1, pn_w1, pn_b1, cbat, nbat);
    k_enc_n<12, false><<<NN, 128, 0, stream>>>(
        x, enc_node_w1, enc_node_b1, enc_node_w2, enc_node_b2, (void*)h);
    k_enc_e_mfma<<<NE / TE, 256, 0, stream>>>(
        edge_attr, enc_edge_w1, enc_edge_b1, W2et, enc_edge_b2, e);

    for (int l = 0; l < NL; ++l) {
        k_zero<<<(NN * H / 4 + 255) / 256, 256, 0, stream>>>(agg, NN * H / 4);
        k_gemm_dual<<<dim3((NN + CH - 1) / CH, 2), 128, 0, stream>>>(
            h, pe_w1 + (size_t)l * 512 * H, pe_w1 + ((size_t)l * 512 + 128) * H, hA, hB);
        k_edge_mfma<<<NE / TE, 256, 0, stream>>>(
            hA, hB, cbat + l * NB * H,
            W1t + (size_t)l * H * H, W2t + (size_t)l * H * H,
            pe_b2 + l * H, rowi, coli, batch, e, agg);
        k_node<<<(NN + CH - 1) / CH, 128, 0, stream>>>(
            pn_w1 + (size_t)l * 384 * H, pn_w1 + ((size_t)l * 384 + 128) * H,
            pn_w2 + (size_t)l * H * H, pn_b2 + l * H,
            nbat + l * NB * H, batch, agg, h);
    }
    k_dec_n<<<NN, 128, 0, stream>>>(h, dec_w1, dec_b1, dec_w2, dec_b2, out);
}

// Round 3
// 2447.524 us; speedup vs baseline: 3.4837x; 1.3575x over previous
//
#include <hip/hip_runtime.h>
#include <cstddef>

#define NN 50000
#define NNP 50048   // NN padded to multiple of TE (node arrays in workspace)
#define NE 640000
#define NB 4
#define H  128
#define NL 4
#define TE 64   // rows per block for MFMA kernels

typedef unsigned int u32;
typedef unsigned short u16;   // raw bf16 (intermediates only; I/O is fp32)
typedef __attribute__((ext_vector_type(8))) short bf16x8;
typedef __attribute__((ext_vector_type(4))) float f32x4;

__device__ __forceinline__ float bf2f(u16 s) {
    union { u32 u; float f; } v; v.u = ((u32)s) << 16; return v.f;
}
__device__ __forceinline__ u16 f2bf(float f) {
    union { float f; u32 u; } v; v.f = f;
    u32 u = v.u;
    u += 0x7FFF + ((u >> 16) & 1);   // RNE
    return (u16)(u >> 16);
}
__device__ __forceinline__ void unpack8(uint4 raw, float* d) {
    d[0] = bf2f(raw.x & 0xFFFF); d[1] = bf2f(raw.x >> 16);
    d[2] = bf2f(raw.y & 0xFFFF); d[3] = bf2f(raw.y >> 16);
    d[4] = bf2f(raw.z & 0xFFFF); d[5] = bf2f(raw.z >> 16);
    d[6] = bf2f(raw.w & 0xFFFF); d[7] = bf2f(raw.w >> 16);
}
// fp32 row-slice (8 floats, 16B-aligned) -> bf16x8 A-fragment
__device__ __forceinline__ bf16x8 ld_f32_bf8(const float* __restrict__ p) {
    const float4 a = *(const float4*)p;
    const float4 b = *(const float4*)(p + 4);
    bf16x8 r;
    r[0] = (short)f2bf(a.x); r[1] = (short)f2bf(a.y);
    r[2] = (short)f2bf(a.z); r[3] = (short)f2bf(a.w);
    r[4] = (short)f2bf(b.x); r[5] = (short)f2bf(b.y);
    r[6] = (short)f2bf(b.z); r[7] = (short)f2bf(b.w);
    return r;
}

// ---------------------------------------------------------------------------
__global__ __launch_bounds__(256) void k_zero(float* __restrict__ p, int n4) {
    const int i = blockIdx.x * 256 + threadIdx.x;
    if (i < n4) ((float4*)p)[i] = make_float4(0.f, 0.f, 0.f, 0.f);
}

// ---------------------------------------------------------------------------
// k_prep: weights -> bf16, transposed to [n][k] for contiguous MFMA B-frags.
// grid (NL, 8); y selects which weight, li = layer (or sub-select for y=7).
// ---------------------------------------------------------------------------
__global__ __launch_bounds__(256) void k_prep(
    const float* __restrict__ pe_w1, const float* __restrict__ pe_w2,
    const float* __restrict__ pn_w1, const float* __restrict__ pn_w2,
    const float* __restrict__ ew2,   const float* __restrict__ nw2,
    u16* __restrict__ W1t, u16* __restrict__ W2t,
    u16* __restrict__ WaT, u16* __restrict__ WbT,
    u16* __restrict__ Wn1aT, u16* __restrict__ Wn1bT, u16* __restrict__ Wn2T,
    u16* __restrict__ W2et, u16* __restrict__ W2nt) {
    const int li = blockIdx.x;
    const float* src; u16* dst;
    switch (blockIdx.y) {
        case 0: src = pe_w1 + ((size_t)li * 512 + 256) * H; dst = W1t  + (size_t)li * H * H; break;
        case 1: src = pe_w2 + (size_t)li * H * H;           dst = W2t  + (size_t)li * H * H; break;
        case 2: src = pe_w1 + (size_t)li * 512 * H;         dst = WaT  + (size_t)li * H * H; break;
        case 3: src = pe_w1 + ((size_t)li * 512 + 128) * H; dst = WbT  + (size_t)li * H * H; break;
        case 4: src = pn_w1 + (size_t)li * 384 * H;         dst = Wn1aT + (size_t)li * H * H; break;
        case 5: src = pn_w1 + ((size_t)li * 384 + 128) * H; dst = Wn1bT + (size_t)li * H * H; break;
        case 6: src = pn_w2 + (size_t)li * H * H;           dst = Wn2T + (size_t)li * H * H; break;
        default:
            if (li == 0)      { src = ew2; dst = W2et; }
            else if (li == 1) { src = nw2; dst = W2nt; }
            else return;
            break;
    }
    for (int idx = threadIdx.x; idx < H * H; idx += 256) {
        const int n = idx >> 7, k = idx & 127;
        dst[idx] = f2bf(src[(size_t)k * H + n]);
    }
}

// ---------------------------------------------------------------------------
// k_small (verified R13): u, x_cond, per-layer consts cbat/nbat.
// ---------------------------------------------------------------------------
__global__ __launch_bounds__(128) void k_small(
    const float* __restrict__ cond,
    const float* __restrict__ ecw1, const float* __restrict__ ecb1,
    const float* __restrict__ ecw2, const float* __restrict__ ecb2,
    const float* __restrict__ wv, const float* __restrict__ bv,
    const float* __restrict__ wo, const float* __restrict__ bo,
    const float* __restrict__ pe_w1, const float* __restrict__ pe_b1,
    const float* __restrict__ pn_w1, const float* __restrict__ pn_b1,
    float* __restrict__ cbat, float* __restrict__ nbat) {
    __shared__ float tmp[NB][H];
    __shared__ float uL[NB][H];
    __shared__ float xcL[NB][H];
    const int t = threadIdx.x;
    for (int b = 0; b < NB; ++b) {
        float a = ecb1[t];
        for (int k = 0; k < 10; ++k) a = fmaf(cond[b * 10 + k], ecw1[k * H + t], a);
        tmp[b][t] = fmaxf(a, 0.f);
    }
    __syncthreads();
    for (int b = 0; b < NB; ++b) {
        float a = ecb2[t];
        for (int k = 0; k < H; ++k) a = fmaf(tmp[b][k], ecw2[k * H + t], a);
        uL[b][t] = a;
    }
    __syncthreads();
    for (int b = 0; b < NB; ++b) {
        float a = bv[t];
        for (int k = 0; k < H; ++k) a = fmaf(uL[b][k], wv[k * H + t], a);
        tmp[b][t] = a;
    }
    __syncthreads();
    for (int b = 0; b < NB; ++b) {
        float a = bo[t];
        for (int k = 0; k < H; ++k) a = fmaf(tmp[b][k], wo[k * H + t], a);
        xcL[b][t] = a;
    }
    __syncthreads();
    for (int l = 0; l < NL; ++l) {
        const float* w1u = pe_w1 + ((size_t)l * 512 + 384) * H;
        for (int b = 0; b < NB; ++b) {
            float a = pe_b1[l * H + t];
            for (int k = 0; k < H; ++k) a = fmaf(uL[b][k], w1u[k * H + t], a);
            cbat[(l * NB + b) * H + t] = a;
        }
        const float* w1x = pn_w1 + ((size_t)l * 384 + 256) * H;
        for (int b = 0; b < NB; ++b) {
            float a = pn_b1[l * H + t];
            for (int k = 0; k < H; ++k) a = fmaf(xcL[b][k], w1x[k * H + t], a);
            nbat[(l * NB + b) * H + t] = a;
        }
    }
}

// ---------------------------------------------------------------------------
// k_dec_n: decoder, verified R13 naive version (small, ~100 µs).
// ---------------------------------------------------------------------------
__global__ __launch_bounds__(128) void k_dec_n(
    const float* __restrict__ h,
    const float* __restrict__ w1, const float* __restrict__ b1,
    const float* __restrict__ w2, const float* __restrict__ b2,
    float* __restrict__ out) {
    __shared__ float hid[H];
    const int t = threadIdx.x;
    const long long n = blockIdx.x;
    float a = b1[t];
    for (int k = 0; k < H; ++k) a = fmaf(h[n * H + k], w1[k * H + t], a);
    hid[t] = fmaxf(a, 0.f);
    __syncthreads();
    if (t < 3) {
        float v = b2[t];
        for (int k = 0; k < H; ++k) v = fmaf(hid[k], w2[k * 3 + t], v);
        out[n * 3 + t] = v;
    }
}

// ---------------------------------------------------------------------------
// k_enc_e_mfma: edge encoder (verified R2). 64 edges/block, 4 waves.
// ---------------------------------------------------------------------------
__global__ __launch_bounds__(256) void k_enc_e_mfma(
    const float* __restrict__ ea,                         // [E,4]
    const float* __restrict__ w1, const float* __restrict__ b1,
    const u16* __restrict__ W2et, const float* __restrict__ b2,
    u16* __restrict__ e) {
    __shared__ float SI[TE][H + 4];
    const int t = threadIdx.x;
    const long long e0 = (long long)blockIdx.x * TE;
    const int w = t >> 6, l = t & 63;
    const int m16 = l & 15, g = l >> 4;
    const int row = w * 16 + m16;

    const float4 av = *(const float4*)&ea[(size_t)(e0 + row) * 4];

    bf16x8 afrag[4];
#pragma unroll
    for (int ks = 0; ks < 4; ++ks) {
        const int c0 = ks * 32 + g * 8;
        float hv[8];
        {
            const float4 ba = *(const float4*)&b1[c0];
            const float4 bb = *(const float4*)&b1[c0 + 4];
            hv[0] = ba.x; hv[1] = ba.y; hv[2] = ba.z; hv[3] = ba.w;
            hv[4] = bb.x; hv[5] = bb.y; hv[6] = bb.z; hv[7] = bb.w;
        }
#pragma unroll
        for (int k = 0; k < 4; ++k) {
            const float s = (k == 0) ? av.x : (k == 1) ? av.y : (k == 2) ? av.z : av.w;
            const float4 wa = *(const float4*)&w1[k * H + c0];
            const float4 wb = *(const float4*)&w1[k * H + c0 + 4];
            hv[0] = fmaf(s, wa.x, hv[0]); hv[1] = fmaf(s, wa.y, hv[1]);
            hv[2] = fmaf(s, wa.z, hv[2]); hv[3] = fmaf(s, wa.w, hv[3]);
            hv[4] = fmaf(s, wb.x, hv[4]); hv[5] = fmaf(s, wb.y, hv[5]);
            hv[6] = fmaf(s, wb.z, hv[6]); hv[7] = fmaf(s, wb.w, hv[7]);
        }
#pragma unroll
        for (int j = 0; j < 8; ++j) afrag[ks][j] = (short)f2bf(fmaxf(hv[j], 0.f));
    }

    f32x4 acc[8];
#pragma unroll
    for (int nt = 0; nt < 8; ++nt) {
        const float bb = b2[nt * 16 + m16];
        acc[nt][0] = bb; acc[nt][1] = bb; acc[nt][2] = bb; acc[nt][3] = bb;
    }
#pragma unroll
    for (int ks = 0; ks < 4; ++ks) {
#pragma unroll
        for (int nt = 0; nt < 8; ++nt) {
            const bf16x8 bfr =
                *(const bf16x8*)&W2et[(size_t)(nt * 16 + m16) * H + ks * 32 + g * 8];
            acc[nt] = __builtin_amdgcn_mfma_f32_16x16x32_bf16(afrag[ks], bfr, acc[nt], 0, 0, 0);
        }
    }

#pragma unroll
    for (int nt = 0; nt < 8; ++nt)
#pragma unroll
        for (int j = 0; j < 4; ++j)
            SI[w * 16 + g * 4 + j][nt * 16 + m16] = acc[nt][j];
    __syncthreads();
    for (int u = t; u < TE * 16; u += 256) {
        const int j = u >> 4, c8 = (u & 15) * 8;
        const float* sp = &SI[j][c8];
        uint4 pk;
        pk.x = (u32)f2bf(sp[0]) | ((u32)f2bf(sp[1]) << 16);
        pk.y = (u32)f2bf(sp[2]) | ((u32)f2bf(sp[3]) << 16);
        pk.z = (u32)f2bf(sp[4]) | ((u32)f2bf(sp[5]) << 16);
        pk.w = (u32)f2bf(sp[6]) | ((u32)f2bf(sp[7]) << 16);
        *(uint4*)&e[(size_t)(e0 + j) * H + c8] = pk;
    }
}

// ---------------------------------------------------------------------------
// k_enc_n_mfma: node encoder, K=12 hidden per-lane, layer-2 via MFMA.
// fp32 output to h (padded rows harmless: clamped input, finite values).
// ---------------------------------------------------------------------------
__global__ __launch_bounds__(256) void k_enc_n_mfma(
    const float* __restrict__ x,                          // [N,12]
    const float* __restrict__ w1, const float* __restrict__ b1,
    const u16* __restrict__ W2nt, const float* __restrict__ b2,
    float* __restrict__ h) {
    __shared__ float SI[TE][H + 4];
    const int t = threadIdx.x;
    const long long n0 = (long long)blockIdx.x * TE;
    const int w = t >> 6, l = t & 63;
    const int m16 = l & 15, g = l >> 4;
    const int row = w * 16 + m16;
    const long long nr = (n0 + row < NN) ? (n0 + row) : (NN - 1);

    float av[12];
    {
        const float4 a0 = *(const float4*)&x[nr * 12];
        const float4 a1 = *(const float4*)&x[nr * 12 + 4];
        const float4 a2 = *(const float4*)&x[nr * 12 + 8];
        av[0] = a0.x; av[1] = a0.y; av[2] = a0.z; av[3] = a0.w;
        av[4] = a1.x; av[5] = a1.y; av[6] = a1.z; av[7] = a1.w;
        av[8] = a2.x; av[9] = a2.y; av[10] = a2.z; av[11] = a2.w;
    }

    bf16x8 afrag[4];
#pragma unroll
    for (int ks = 0; ks < 4; ++ks) {
        const int c0 = ks * 32 + g * 8;
        float hv[8];
        {
            const float4 ba = *(const float4*)&b1[c0];
            const float4 bb = *(const float4*)&b1[c0 + 4];
            hv[0] = ba.x; hv[1] = ba.y; hv[2] = ba.z; hv[3] = ba.w;
            hv[4] = bb.x; hv[5] = bb.y; hv[6] = bb.z; hv[7] = bb.w;
        }
#pragma unroll
        for (int k = 0; k < 12; ++k) {
            const float s = av[k];
            const float4 wa = *(const float4*)&w1[k * H + c0];
            const float4 wb = *(const float4*)&w1[k * H + c0 + 4];
            hv[0] = fmaf(s, wa.x, hv[0]); hv[1] = fmaf(s, wa.y, hv[1]);
            hv[2] = fmaf(s, wa.z, hv[2]); hv[3] = fmaf(s, wa.w, hv[3]);
            hv[4] = fmaf(s, wb.x, hv[4]); hv[5] = fmaf(s, wb.y, hv[5]);
            hv[6] = fmaf(s, wb.z, hv[6]); hv[7] = fmaf(s, wb.w, hv[7]);
        }
#pragma unroll
        for (int j = 0; j < 8; ++j) afrag[ks][j] = (short)f2bf(fmaxf(hv[j], 0.f));
    }

    f32x4 acc[8];
#pragma unroll
    for (int nt = 0; nt < 8; ++nt) {
        const float bb = b2[nt * 16 + m16];
        acc[nt][0] = bb; acc[nt][1] = bb; acc[nt][2] = bb; acc[nt][3] = bb;
    }
#pragma unroll
    for (int ks = 0; ks < 4; ++ks) {
#pragma unroll
        for (int nt = 0; nt < 8; ++nt) {
            const bf16x8 bfr =
                *(const bf16x8*)&W2nt[(size_t)(nt * 16 + m16) * H + ks * 32 + g * 8];
            acc[nt] = __builtin_amdgcn_mfma_f32_16x16x32_bf16(afrag[ks], bfr, acc[nt], 0, 0, 0);
        }
    }

#pragma unroll
    for (int nt = 0; nt < 8; ++nt)
#pragma unroll
        for (int j = 0; j < 4; ++j)
            SI[w * 16 + g * 4 + j][nt * 16 + m16] = acc[nt][j];
    __syncthreads();
    for (int u = t; u < TE * H / 4; u += 256) {
        const int j = u >> 5, c4 = (u & 31) * 4;
        *(float4*)&h[(size_t)(n0 + j) * H + c4] = *(const float4*)&SI[j][c4];
    }
}

// ---------------------------------------------------------------------------
// k_gemm_dual_mfma: hA = h@Wa, hB = h@Wb in one pass (shared A-fragments).
// 64 nodes/block, 4 waves, bf16 outputs.
// ---------------------------------------------------------------------------
__global__ __launch_bounds__(256) void k_gemm_dual_mfma(
    const float* __restrict__ h,
    const u16* __restrict__ WaT, const u16* __restrict__ WbT,
    u16* __restrict__ Ca, u16* __restrict__ Cb) {
    __shared__ float SI[TE][H + 4];
    const int t = threadIdx.x;
    const long long n0 = (long long)blockIdx.x * TE;
    const int w = t >> 6, l = t & 63;
    const int m16 = l & 15, g = l >> 4;
    const int row = w * 16 + m16;

    bf16x8 afrag[4];
    {
        const float* hp = h + (size_t)(n0 + row) * H + g * 8;
#pragma unroll
        for (int ks = 0; ks < 4; ++ks) afrag[ks] = ld_f32_bf8(hp + ks * 32);
    }

    f32x4 accA[8], accB[8];
#pragma unroll
    for (int nt = 0; nt < 8; ++nt) {
        accA[nt][0] = 0.f; accA[nt][1] = 0.f; accA[nt][2] = 0.f; accA[nt][3] = 0.f;
        accB[nt][0] = 0.f; accB[nt][1] = 0.f; accB[nt][2] = 0.f; accB[nt][3] = 0.f;
    }
#pragma unroll
    for (int ks = 0; ks < 4; ++ks) {
#pragma unroll
        for (int nt = 0; nt < 8; ++nt) {
            const size_t off = (size_t)(nt * 16 + m16) * H + ks * 32 + g * 8;
            const bf16x8 ba = *(const bf16x8*)&WaT[off];
            const bf16x8 bb = *(const bf16x8*)&WbT[off];
            accA[nt] = __builtin_amdgcn_mfma_f32_16x16x32_bf16(afrag[ks], ba, accA[nt], 0, 0, 0);
            accB[nt] = __builtin_amdgcn_mfma_f32_16x16x32_bf16(afrag[ks], bb, accB[nt], 0, 0, 0);
        }
    }

#pragma unroll
    for (int s = 0; s < 2; ++s) {
        __syncthreads();   // protect SI reuse across the two stores
#pragma unroll
        for (int nt = 0; nt < 8; ++nt)
#pragma unroll
            for (int j = 0; j < 4; ++j)
                SI[w * 16 + g * 4 + j][nt * 16 + m16] = s ? accB[nt][j] : accA[nt][j];
        __syncthreads();
        u16* C = s ? Cb : Ca;
        for (int u = t; u < TE * 16; u += 256) {
            const int j = u >> 4, c8 = (u & 15) * 8;
            const float* sp = &SI[j][c8];
            uint4 pk;
            pk.x = (u32)f2bf(sp[0]) | ((u32)f2bf(sp[1]) << 16);
            pk.y = (u32)f2bf(sp[2]) | ((u32)f2bf(sp[3]) << 16);
            pk.z = (u32)f2bf(sp[4]) | ((u32)f2bf(sp[5]) << 16);
            pk.w = (u32)f2bf(sp[6]) | ((u32)f2bf(sp[7]) << 16);
            *(uint4*)&C[(size_t)(n0 + j) * H + c8] = pk;
        }
    }
}

// ---------------------------------------------------------------------------
// k_edge_mfma (verified R1/R2): 64 edges/block, 4 waves.
// ---------------------------------------------------------------------------
__global__ __launch_bounds__(256) void k_edge_mfma(
    const u16* __restrict__ hA, const u16* __restrict__ hB,
    const float* __restrict__ cbatl,
    const u16* __restrict__ W1t, const u16* __restrict__ W2t,
    const float* __restrict__ b2,
    const int* __restrict__ rowi, const int* __restrict__ coli,
    const int* __restrict__ batch,
    u16* __restrict__ e, float* __restrict__ agg) {
    __shared__ float SI[TE][H + 4];      // acc-init -> hidden -> output staging
    __shared__ int rL[TE], cL[TE], bL[TE];
    const int t = threadIdx.x;
    const long long e0 = (long long)blockIdx.x * TE;

    if (t < TE) {
        const int r = rowi[e0 + t];
        rL[t] = r; bL[t] = batch[r];
    } else if (t < 2 * TE) {
        cL[t - TE] = coli[e0 + t - TE];
    }
    __syncthreads();

    for (int u = t; u < TE * 16; u += 256) {
        const int j = u >> 4, c8 = (u & 15) * 8;
        float va[8], vb[8];
        unpack8(*(const uint4*)&hA[(size_t)rL[j] * H + c8], va);
        unpack8(*(const uint4*)&hB[(size_t)cL[j] * H + c8], vb);
        const float* cb = &cbatl[bL[j] * H + c8];
#pragma unroll
        for (int q = 0; q < 8; ++q) SI[j][c8 + q] = va[q] + vb[q] + cb[q];
    }

    const int w = t >> 6, l = t & 63;
    const int m16 = l & 15, g = l >> 4;

    bf16x8 afrag[4];
    {
        const u16* ep = e + (size_t)(e0 + w * 16 + m16) * H + g * 8;
#pragma unroll
        for (int ks = 0; ks < 4; ++ks) afrag[ks] = *(const bf16x8*)(ep + ks * 32);
    }
    __syncthreads();   // SI fill visible

    f32x4 acc[8];
#pragma unroll
    for (int nt = 0; nt < 8; ++nt) {
#pragma unroll
        for (int j = 0; j < 4; ++j)
            acc[nt][j] = SI[w * 16 + g * 4 + j][nt * 16 + m16];
#pragma unroll
        for (int ks = 0; ks < 4; ++ks) {
            const bf16x8 bfr =
                *(const bf16x8*)&W1t[(size_t)(nt * 16 + m16) * H + ks * 32 + g * 8];
            acc[nt] = __builtin_amdgcn_mfma_f32_16x16x32_bf16(afrag[ks], bfr, acc[nt], 0, 0, 0);
        }
    }
    __syncthreads();

#pragma unroll
    for (int nt = 0; nt < 8; ++nt)
#pragma unroll
        for (int j = 0; j < 4; ++j)
            SI[w * 16 + g * 4 + j][nt * 16 + m16] = fmaxf(acc[nt][j], 0.f);
    __syncthreads();

    f32x4 acc2[8];
#pragma unroll
    for (int nt = 0; nt < 8; ++nt) {
        const float bb = b2[nt * 16 + m16];
        acc2[nt][0] = bb; acc2[nt][1] = bb; acc2[nt][2] = bb; acc2[nt][3] = bb;
    }
#pragma unroll
    for (int ks = 0; ks < 4; ++ks) {
        bf16x8 a2;
        const float* hp = &SI[w * 16 + m16][ks * 32 + g * 8];
#pragma unroll
        for (int j = 0; j < 8; ++j) a2[j] = (short)f2bf(hp[j]);
#pragma unroll
        for (int nt = 0; nt < 8; ++nt) {
            const bf16x8 bfr =
                *(const bf16x8*)&W2t[(size_t)(nt * 16 + m16) * H + ks * 32 + g * 8];
            acc2[nt] = __builtin_amdgcn_mfma_f32_16x16x32_bf16(a2, bfr, acc2[nt], 0, 0, 0);
        }
    }
    __syncthreads();   // hidden reads done before overwrite

#pragma unroll
    for (int nt = 0; nt < 8; ++nt)
#pragma unroll
        for (int j = 0; j < 4; ++j)
            SI[w * 16 + g * 4 + j][nt * 16 + m16] = acc2[nt][j];
    __syncthreads();

    for (int u = t; u < TE * 16; u += 256) {
        const int j = u >> 4, c8 = (u & 15) * 8;
        const float* sp = &SI[j][c8];
        uint4 pk;
        pk.x = (u32)f2bf(sp[0]) | ((u32)f2bf(sp[1]) << 16);
        pk.y = (u32)f2bf(sp[2]) | ((u32)f2bf(sp[3]) << 16);
        pk.z = (u32)f2bf(sp[4]) | ((u32)f2bf(sp[5]) << 16);
        pk.w = (u32)f2bf(sp[6]) | ((u32)f2bf(sp[7]) << 16);
        *(uint4*)&e[(size_t)(e0 + j) * H + c8] = pk;
    }
    for (int idx = t; idx < TE * H; idx += 256) {
        const int j = idx >> 7, c = idx & 127;
        atomicAdd(&agg[(size_t)rL[j] * H + c], SI[j][c]);
    }
}

// ---------------------------------------------------------------------------
// k_node_mfma: h += relu(h@Wn1a + agg@Wn1b + nbat[batch]) @ Wn2 + bn2
// 64 nodes/block, 4 waves; fp32 h/agg converted to bf16 frags on the fly.
// ---------------------------------------------------------------------------
__global__ __launch_bounds__(256) void k_node_mfma(
    const u16* __restrict__ Wn1aT, const u16* __restrict__ Wn1bT,
    const u16* __restrict__ Wn2T, const float* __restrict__ bn2,
    const float* __restrict__ nbatl, const int* __restrict__ batch,
    const float* __restrict__ agg, float* __restrict__ h) {
    __shared__ float SI[TE][H + 4];
    __shared__ float NBl[NB][H];
    __shared__ int bL[TE];
    const int t = threadIdx.x;
    const long long n0 = (long long)blockIdx.x * TE;
    if (t < TE) {
        const long long n = n0 + t;
        bL[t] = batch[n < NN ? n : (NN - 1)];
    }
    for (int i = t; i < NB * H; i += 256) ((float*)NBl)[i] = nbatl[i];

    const int w = t >> 6, l = t & 63;
    const int m16 = l & 15, g = l >> 4;
    const int row = w * 16 + m16;

    bf16x8 afrag[4];
    {
        const float* hp = h + (size_t)(n0 + row) * H + g * 8;
#pragma unroll
        for (int ks = 0; ks < 4; ++ks) afrag[ks] = ld_f32_bf8(hp + ks * 32);
    }
    __syncthreads();   // bL / NBl visible

    f32x4 acc[8];
#pragma unroll
    for (int nt = 0; nt < 8; ++nt)
#pragma unroll
        for (int j = 0; j < 4; ++j)
            acc[nt][j] = NBl[bL[w * 16 + g * 4 + j]][nt * 16 + m16];

#pragma unroll
    for (int ks = 0; ks < 4; ++ks)
#pragma unroll
        for (int nt = 0; nt < 8; ++nt) {
            const bf16x8 bfr =
                *(const bf16x8*)&Wn1aT[(size_t)(nt * 16 + m16) * H + ks * 32 + g * 8];
            acc[nt] = __builtin_amdgcn_mfma_f32_16x16x32_bf16(afrag[ks], bfr, acc[nt], 0, 0, 0);
        }

    {
        const float* ap = agg + (size_t)(n0 + row) * H + g * 8;
#pragma unroll
        for (int ks = 0; ks < 4; ++ks) afrag[ks] = ld_f32_bf8(ap + ks * 32);
    }
#pragma unroll
    for (int ks = 0; ks < 4; ++ks)
#pragma unroll
        for (int nt = 0; nt < 8; ++nt) {
            const bf16x8 bfr =
                *(const bf16x8*)&Wn1bT[(size_t)(nt * 16 + m16) * H + ks * 32 + g * 8];
            acc[nt] = __builtin_amdgcn_mfma_f32_16x16x32_bf16(afrag[ks], bfr, acc[nt], 0, 0, 0);
        }

    // hidden = relu(acc) -> SI
#pragma unroll
    for (int nt = 0; nt < 8; ++nt)
#pragma unroll
        for (int j = 0; j < 4; ++j)
            SI[w * 16 + g * 4 + j][nt * 16 + m16] = fmaxf(acc[nt][j], 0.f);
    __syncthreads();

    f32x4 acc2[8];
#pragma unroll
    for (int nt = 0; nt < 8; ++nt) {
        const float bb = bn2[nt * 16 + m16];
        acc2[nt][0] = bb; acc2[nt][1] = bb; acc2[nt][2] = bb; acc2[nt][3] = bb;
    }
#pragma unroll
    for (int ks = 0; ks < 4; ++ks) {
        bf16x8 a2;
        const float* hp = &SI[w * 16 + m16][ks * 32 + g * 8];
#pragma unroll
        for (int j = 0; j < 8; ++j) a2[j] = (short)f2bf(hp[j]);
#pragma unroll
        for (int nt = 0; nt < 8; ++nt) {
            const bf16x8 bfr =
                *(const bf16x8*)&Wn2T[(size_t)(nt * 16 + m16) * H + ks * 32 + g * 8];
            acc2[nt] = __builtin_amdgcn_mfma_f32_16x16x32_bf16(a2, bfr, acc2[nt], 0, 0, 0);
        }
    }
    __syncthreads();   // hidden reads done before overwrite

#pragma unroll
    for (int nt = 0; nt < 8; ++nt)
#pragma unroll
        for (int j = 0; j < 4; ++j)
            SI[w * 16 + g * 4 + j][nt * 16 + m16] = acc2[nt][j];
    __syncthreads();

    // h += (coalesced float4 RMW)
    for (int u = t; u < TE * H / 4; u += 256) {
        const int j = u >> 5, c4 = (u & 31) * 4;
        float4 hv = *(const float4*)&h[(size_t)(n0 + j) * H + c4];
        const float4 sv = *(const float4*)&SI[j][c4];
        hv.x += sv.x; hv.y += sv.y; hv.z += sv.z; hv.w += sv.w;
        *(float4*)&h[(size_t)(n0 + j) * H + c4] = hv;
    }
}

// ---------------------------------------------------------------------------
extern "C" void kernel_launch(void* const* d_in, const int* in_sizes, int n_in,
                              void* d_out, int out_size, void* d_ws, size_t ws_size,
                              hipStream_t stream) {
    const float* x          = (const float*)d_in[0];
    const int*   edge_index = (const int*)d_in[1];
    const float* edge_attr  = (const float*)d_in[2];
    const float* cond       = (const float*)d_in[3];
    const int*   batch      = (const int*)d_in[4];
    const float* enc_node_w1 = (const float*)d_in[5];
    const float* enc_node_b1 = (const float*)d_in[6];
    const float* enc_node_w2 = (const float*)d_in[7];
    const float* enc_node_b2 = (const float*)d_in[8];
    const float* enc_edge_w1 = (const float*)d_in[9];
    const float* enc_edge_b1 = (const float*)d_in[10];
    const float* enc_edge_w2 = (const float*)d_in[11];
    const float* enc_edge_b2 = (const float*)d_in[12];
    const float* enc_cond_w1 = (const float*)d_in[13];
    const float* enc_cond_b1 = (const float*)d_in[14];
    const float* enc_cond_w2 = (const float*)d_in[15];
    const float* enc_cond_b2 = (const float*)d_in[16];
    const float* attn_wv = (const float*)d_in[17];
    const float* attn_bv = (const float*)d_in[18];
    const float* attn_wo = (const float*)d_in[19];
    const float* attn_bo = (const float*)d_in[20];
    const float* pe_w1 = (const float*)d_in[21];
    const float* pe_b1 = (const float*)d_in[22];
    const float* pe_w2 = (const float*)d_in[23];
    const float* pe_b2 = (const float*)d_in[24];
    const float* pn_w1 = (const float*)d_in[25];
    const float* pn_b1 = (const float*)d_in[26];
    const float* pn_w2 = (const float*)d_in[27];
    const float* pn_b2 = (const float*)d_in[28];
    const float* dec_w1 = (const float*)d_in[29];
    const float* dec_b1 = (const float*)d_in[30];
    const float* dec_w2 = (const float*)d_in[31];
    const float* dec_b2 = (const float*)d_in[32];

    // workspace (~241.7 MB): node arrays padded to NNP rows
    u16*   e    = (u16*)d_ws;                                  // NE*H bf16
    float* h    = (float*)((char*)d_ws + (size_t)NE * H * 2);  // NNP*H f32
    float* agg  = h + (size_t)NNP * H;                         // NNP*H f32
    u16*   hA   = (u16*)(agg + (size_t)NNP * H);               // NNP*H bf16
    u16*   hB   = hA + (size_t)NNP * H;                        // NNP*H bf16
    float* cbat = (float*)(hB + (size_t)NNP * H);              // NL*NB*H f32
    float* nbat = cbat + NL * NB * H;                          // NL*NB*H f32
    u16*   W1t   = (u16*)(nbat + NL * NB * H);                 // NL*H*H bf16 each:
    u16*   W2t   = W1t  + (size_t)NL * H * H;
    u16*   WaT   = W2t  + (size_t)NL * H * H;
    u16*   WbT   = WaT  + (size_t)NL * H * H;
    u16*   Wn1aT = WbT  + (size_t)NL * H * H;
    u16*   Wn1bT = Wn1aT + (size_t)NL * H * H;
    u16*   Wn2T  = Wn1bT + (size_t)NL * H * H;
    u16*   W2et  = Wn2T + (size_t)NL * H * H;                  // H*H bf16
    u16*   W2nt  = W2et + (size_t)H * H;                       // H*H bf16

    const int* rowi = edge_index;
    const int* coli = edge_index + NE;
    float* out = (float*)d_out;

    k_prep<<<dim3(NL, 8), 256, 0, stream>>>(pe_w1, pe_w2, pn_w1, pn_w2,
                                            enc_edge_w2, enc_node_w2,
                                            W1t, W2t, WaT, WbT,
                                            Wn1aT, Wn1bT, Wn2T, W2et, W2nt);
    k_small<<<1, 128, 0, stream>>>(cond, enc_cond_w1, enc_cond_b1, enc_cond_w2, enc_cond_b2,
                                   attn_wv, attn_bv, attn_wo, attn_bo,
                                   pe_w1, pe_b1, pn_w1, pn_b1, cbat, nbat);
    k_enc_n_mfma<<<NNP / TE, 256, 0, stream>>>(
        x, enc_node_w1, enc_node_b1, W2nt, enc_node_b2, h);
    k_enc_e_mfma<<<NE / TE, 256, 0, stream>>>(
        edge_attr, enc_edge_w1, enc_edge_b1, W2et, enc_edge_b2, e);

    for (int l = 0; l < NL; ++l) {
        k_zero<<<(NNP * H / 4 + 255) / 256, 256, 0, stream>>>(agg, NNP * H / 4);
        k_gemm_dual_mfma<<<NNP / TE, 256, 0, stream>>>(h, WaT + (size_t)l * H * H,
                                                       WbT + (size_t)l * H * H, hA, hB);
        k_edge_mfma<<<NE / TE, 256, 0, stream>>>(
            hA, hB, cbat + l * NB * H,
            W1t + (size_t)l * H * H, W2t + (size_t)l * H * H,
            pe_b2 + l * H, rowi, coli, batch, e, agg);
        k_node_mfma<<<NNP / TE, 256, 0, stream>>>(
            Wn1aT + (size_t)l * H * H, Wn1bT + (size_t)l * H * H,
            Wn2T + (size_t)l * H * H, pn_b2 + l * H,
            nbat + l * NB * H, batch, agg, h);
    }
    k_dec_n<<<NN, 128, 0, stream>>>(h, dec_w1, dec_b1, dec_w2, dec_b2, out);
}